// Round 8
// baseline (158.621 us; speedup 1.0000x reference)
//
#include <hip/hip_runtime.h>
#include <hip/hip_bf16.h>
#include <stdint.h>

typedef __attribute__((ext_vector_type(8))) short bf16x8;
typedef __attribute__((ext_vector_type(4))) float f32x4;
typedef __attribute__((ext_vector_type(4))) unsigned int u32x4;
typedef __attribute__((ext_vector_type(2))) unsigned int u32x2;
typedef unsigned short u16;
typedef unsigned int u32;

#define N_NODES 8192
#define N_EDGES 1024
#define F_DIM   256

__device__ __forceinline__ u16 f2bf(float f) {
    union { float f; u32 u; } v; v.f = f;
    u32 u = v.u;
    u = (u + 0x7FFFu + ((u >> 16) & 1u)) >> 16;   // round-nearest-even
    return (u16)u;
}

// async 16B global -> LDS (direct-to-shared DMA; m97 ladder step).
// LDS dest semantics: wave-uniform base + lane*16 (no padding possible).
__device__ __forceinline__ void async16(const u16* g, u16* l) {
    __builtin_amdgcn_global_load_lds(
        (const __attribute__((address_space(1))) u32*)(const void*)g,
        (__attribute__((address_space(3))) u32*)(void*)l, 16, 0, 0);
}

// ---------------------------------------------------------------------------
// prep_h — R1/R6/R7 verbatim.
// One pass over H [8192 x 1024] fp32:
//   - Hb [8192 x 1024] bf16 (row-major, A-operand of GEMM2)
//   - Ht [1024 x 8192] bf16 (transposed via LDS, Bt-operand of GEMM1)
//   - dv[8192] row sums, de[1024] col sums (exact: sums of 0/1)
// ---------------------------------------------------------------------------
__global__ void prep_h(const float* __restrict__ H, u16* __restrict__ Hb,
                       u16* __restrict__ Ht, float* __restrict__ dv,
                       float* __restrict__ de) {
    __shared__ u16 tT[64 * 66];
    __shared__ float dv_s[64];
    __shared__ float de_s[64];
    const int tid = threadIdx.x;
    if (tid < 64) { dv_s[tid] = 0.f; de_s[tid] = 0.f; }
    __syncthreads();
    const int r0 = blockIdx.y * 64;
    const int c0 = blockIdx.x * 64;
    const int lr = tid >> 4;
    const int lc = (tid & 15) * 4;
    float cs0 = 0.f, cs1 = 0.f, cs2 = 0.f, cs3 = 0.f;
#pragma unroll
    for (int i = 0; i < 4; i++) {
        const int row = r0 + lr + i * 16;
        f32x4 v = *(const f32x4*)(&H[(size_t)row * N_EDGES + c0 + lc]);
        atomicAdd(&dv_s[lr + i * 16], v[0] + v[1] + v[2] + v[3]);
        cs0 += v[0]; cs1 += v[1]; cs2 += v[2]; cs3 += v[3];
        const u16 b0 = f2bf(v[0]), b1 = f2bf(v[1]), b2 = f2bf(v[2]), b3 = f2bf(v[3]);
        u32x2 pk; pk[0] = (u32)b0 | ((u32)b1 << 16); pk[1] = (u32)b2 | ((u32)b3 << 16);
        *(u32x2*)(&Hb[(size_t)row * N_EDGES + c0 + lc]) = pk;
        tT[(lc + 0) * 66 + lr + i * 16] = b0;
        tT[(lc + 1) * 66 + lr + i * 16] = b1;
        tT[(lc + 2) * 66 + lr + i * 16] = b2;
        tT[(lc + 3) * 66 + lr + i * 16] = b3;
    }
    atomicAdd(&de_s[lc + 0], cs0);
    atomicAdd(&de_s[lc + 1], cs1);
    atomicAdd(&de_s[lc + 2], cs2);
    atomicAdd(&de_s[lc + 3], cs3);
    __syncthreads();
    if (tid < 64) {
        atomicAdd(&dv[r0 + tid], dv_s[tid]);
        atomicAdd(&de[c0 + tid], de_s[tid]);
    }
#pragma unroll
    for (int i = 0; i < 4; i++) {
        const int er = lr + i * 16;
        const u16 b0 = tT[er * 66 + lc + 0];
        const u16 b1 = tT[er * 66 + lc + 1];
        const u16 b2 = tT[er * 66 + lc + 2];
        const u16 b3 = tT[er * 66 + lc + 3];
        u32x2 pk; pk[0] = (u32)b0 | ((u32)b1 << 16); pk[1] = (u32)b2 | ((u32)b3 << 16);
        *(u32x2*)(&Ht[(size_t)(c0 + er) * N_NODES + r0 + lc]) = pk;
    }
}

// ---------------------------------------------------------------------------
// prep_x — verbatim. Xst[f][n] = bf16(X[n][f]*rsqrt(dv[n])) [256 x 8192]
// ---------------------------------------------------------------------------
__global__ void prep_x(const float* __restrict__ X, const float* __restrict__ dv,
                       u16* __restrict__ Xst) {
    __shared__ u16 tT[64 * 66];
    const int tid = threadIdx.x;
    const int r0 = blockIdx.y * 64;
    const int c0 = blockIdx.x * 64;
    const int lr = tid >> 4;
    const int lc = (tid & 15) * 4;
#pragma unroll
    for (int i = 0; i < 4; i++) {
        const int row = r0 + lr + i * 16;
        const float s = rsqrtf(dv[row]);
        f32x4 v = *(const f32x4*)(&X[(size_t)row * F_DIM + c0 + lc]);
        tT[(lc + 0) * 66 + lr + i * 16] = f2bf(v[0] * s);
        tT[(lc + 1) * 66 + lr + i * 16] = f2bf(v[1] * s);
        tT[(lc + 2) * 66 + lr + i * 16] = f2bf(v[2] * s);
        tT[(lc + 3) * 66 + lr + i * 16] = f2bf(v[3] * s);
    }
    __syncthreads();
#pragma unroll
    for (int i = 0; i < 4; i++) {
        const int er = lr + i * 16;
        const u16 b0 = tT[er * 66 + lc + 0];
        const u16 b1 = tT[er * 66 + lc + 1];
        const u16 b2 = tT[er * 66 + lc + 2];
        const u16 b3 = tT[er * 66 + lc + 3];
        u32x2 pk; pk[0] = (u32)b0 | ((u32)b1 << 16); pk[1] = (u32)b2 | ((u32)b3 << 16);
        *(u32x2*)(&Xst[(size_t)(c0 + er) * N_NODES + r0 + lc]) = pk;
    }
}

// ---------------------------------------------------------------------------
// gemm_bt — R7 body; ONE change: EPI 0 now stores non-atomic per-z partials
// at outF + blockIdx.z*pstride (removes 2.1M 8-way-conflicting atomics).
// EPI 1: fp32 out = v*rsqrt(rowScale[row]) + bias[col]  (GEMM2 final)
// ---------------------------------------------------------------------------
template <int EPI>
__global__ void gemm_bt(const u16* __restrict__ A, const u16* __restrict__ Bt,
                        int lda, int ldb, int kSplit,
                        float* __restrict__ outF, int ldc, int pstride,
                        const float* __restrict__ rowScale,
                        const float* __restrict__ bias) {
    __shared__ __align__(16) u16 As[64 * 64];
    __shared__ __align__(16) u16 Bs[64 * 64];
    const int tid = threadIdx.x;
    const int lane = tid & 63;
    const int wave = tid >> 6;          // 0..3
    const int wm = wave >> 1, wn = wave & 1;
    const int row16 = lane & 15;
    const int quad = lane >> 4;

    const int row0 = blockIdx.y * 64;
    const int col0 = blockIdx.x * 64;
    const int k0 = blockIdx.z * kSplit;
    const int k1 = k0 + kSplit;

    const int srow = lane >> 3;         // 0..7
    const int scol = (lane & 7) * 8;    // u16 units

    const u16* gA0 = A + (size_t)(row0 + wave * 16 + srow) * lda + scol;
    const u16* gB0 = Bt + (size_t)(col0 + wave * 16 + srow) * ldb + scol;
    const size_t rstep8A = (size_t)8 * lda;
    const size_t rstep8B = (size_t)8 * ldb;
    u16* lA0 = &As[(wave * 16) * 64];
    u16* lB0 = &Bs[(wave * 16) * 64];

    f32x4 acc[2][2] = {};

    for (int k = k0; k < k1; k += 64) {
        async16(gA0 + k, lA0);
        async16(gA0 + k + rstep8A, lA0 + 8 * 64);
        async16(gB0 + k, lB0);
        async16(gB0 + k + rstep8B, lB0 + 8 * 64);
        __syncthreads();
#pragma unroll
        for (int ks = 0; ks < 2; ks++) {
            bf16x8 af[2], bfr[2];
#pragma unroll
            for (int t = 0; t < 2; t++) {
                af[t]  = *(const bf16x8*)(&As[(wm * 32 + t * 16 + row16) * 64 + ks * 32 + quad * 8]);
                bfr[t] = *(const bf16x8*)(&Bs[(wn * 32 + t * 16 + row16) * 64 + ks * 32 + quad * 8]);
            }
#pragma unroll
            for (int tm = 0; tm < 2; tm++)
#pragma unroll
                for (int tn = 0; tn < 2; tn++)
                    acc[tm][tn] = __builtin_amdgcn_mfma_f32_16x16x32_bf16(
                        af[tm], bfr[tn], acc[tm][tn], 0, 0, 0);
        }
        __syncthreads();
    }

    float* o = outF + (size_t)blockIdx.z * pstride;
#pragma unroll
    for (int tm = 0; tm < 2; tm++) {
#pragma unroll
        for (int tn = 0; tn < 2; tn++) {
            const int col = col0 + wn * 32 + tn * 16 + row16;
#pragma unroll
            for (int r = 0; r < 4; r++) {
                const int row = row0 + wm * 32 + tm * 16 + quad * 4 + r;
                float v = acc[tm][tn][r];
                if (EPI == 0) {
                    o[(size_t)row * ldc + col] = v;
                } else {
                    o[(size_t)row * ldc + col] =
                        v * rsqrtf(rowScale[row]) + bias[col];
                }
            }
        }
    }
}

// ---------------------------------------------------------------------------
// gemm_we — R6 structure; B-staging now sums P=8 split-K partials (L3-fast)
// before De^-1 scaling. M2t[j][e] = sum_f W[j][f]*(sum_p Mp[p][f][e])/de[e]
// ---------------------------------------------------------------------------
__global__ void gemm_we(const float* __restrict__ W, const float* __restrict__ Maccp,
                        const float* __restrict__ de, u16* __restrict__ M2t) {
    __shared__ u16 As[64 * 72];
    __shared__ u16 Bs[64 * 72];
    const int tid = threadIdx.x;
    const int lane = tid & 63;
    const int wave = tid >> 6;
    const int wm = wave >> 1, wn = wave & 1;
    const int row16 = lane & 15;
    const int quad = lane >> 4;

    const int j0 = blockIdx.y * 64;
    const int e0 = blockIdx.x * 64;

    const int sr = tid >> 2;
    const int fb = (tid & 3) * 16;
    const int lr = tid >> 4;
    const int lc = (tid & 15) * 4;

    f32x4 de4 = *(const f32x4*)(&de[e0 + lc]);
    f32x4 dei = {1.f / de4[0], 1.f / de4[1], 1.f / de4[2], 1.f / de4[3]};

    f32x4 acc[2][2] = {};

    for (int k = 0; k < 256; k += 64) {
#pragma unroll
        for (int s = 0; s < 4; s++) {
            f32x4 w = *(const f32x4*)(&W[(size_t)(j0 + sr) * 256 + k + fb + s * 4]);
            u32x2 pk;
            pk[0] = (u32)f2bf(w[0]) | ((u32)f2bf(w[1]) << 16);
            pk[1] = (u32)f2bf(w[2]) | ((u32)f2bf(w[3]) << 16);
            *(u32x2*)(&As[sr * 72 + fb + s * 4]) = pk;
        }
#pragma unroll
        for (int i = 0; i < 4; i++) {
            const int f = k + lr + i * 16;
            f32x4 m = {0.f, 0.f, 0.f, 0.f};
#pragma unroll
            for (int p = 0; p < 8; p++) {
                f32x4 mp = *(const f32x4*)(&Maccp[(size_t)p * (F_DIM * N_EDGES)
                                                 + (size_t)f * N_EDGES + e0 + lc]);
                m[0] += mp[0]; m[1] += mp[1]; m[2] += mp[2]; m[3] += mp[3];
            }
            Bs[(lc + 0) * 72 + lr + i * 16] = f2bf(m[0] * dei[0]);
            Bs[(lc + 1) * 72 + lr + i * 16] = f2bf(m[1] * dei[1]);
            Bs[(lc + 2) * 72 + lr + i * 16] = f2bf(m[2] * dei[2]);
            Bs[(lc + 3) * 72 + lr + i * 16] = f2bf(m[3] * dei[3]);
        }
        __syncthreads();
#pragma unroll
        for (int ks = 0; ks < 2; ks++) {
            bf16x8 af[2], bfr[2];
#pragma unroll
            for (int i = 0; i < 2; i++)
                af[i] = *(const bf16x8*)(&As[(wm * 32 + i * 16 + row16) * 72 + ks * 32 + quad * 8]);
#pragma unroll
            for (int j = 0; j < 2; j++)
                bfr[j] = *(const bf16x8*)(&Bs[(wn * 32 + j * 16 + row16) * 72 + ks * 32 + quad * 8]);
#pragma unroll
            for (int i = 0; i < 2; i++)
#pragma unroll
                for (int j = 0; j < 2; j++)
                    acc[i][j] = __builtin_amdgcn_mfma_f32_16x16x32_bf16(
                        af[i], bfr[j], acc[i][j], 0, 0, 0);
        }
        __syncthreads();
    }

#pragma unroll
    for (int i = 0; i < 2; i++) {
#pragma unroll
        for (int j = 0; j < 2; j++) {
            const int col = e0 + wn * 32 + j * 16 + row16;
#pragma unroll
            for (int r = 0; r < 4; r++) {
                const int row = j0 + wm * 32 + i * 16 + quad * 4 + r;
                M2t[(size_t)row * N_EDGES + col] = f2bf(acc[i][j][r]);
            }
        }
    }
}

// ---------------------------------------------------------------------------
extern "C" void kernel_launch(void* const* d_in, const int* in_sizes, int n_in,
                              void* d_out, int out_size, void* d_ws, size_t ws_size,
                              hipStream_t stream) {
    (void)in_sizes; (void)n_in; (void)out_size; (void)ws_size;
    const float* X = (const float*)d_in[0];   // [8192 x 256]
    const float* H = (const float*)d_in[1];   // [8192 x 1024]
    const float* W = (const float*)d_in[2];   // [256 x 256]
    const float* b = (const float*)d_in[3];   // [256]
    float* out = (float*)d_out;               // [8192 x 256] fp32

    char* ws = (char*)d_ws;
    float* dv    = (float*)(ws);                // 32 KB
    float* de    = (float*)(ws + 0x8000);       // 4 KB
    float* Maccp = (float*)(ws + 0x10000);      // 8 MB: 8 x [256 x 1024] fp32
    u16*   Hb    = (u16*)(ws + 0x810000);       // 16 MB  [8192 x 1024]
    u16*   Ht    = (u16*)(ws + 0x1810000);      // 16 MB  [1024 x 8192]
    u16*   Xst   = (u16*)(ws + 0x2810000);      // 4 MB   [256 x 8192]
    u16*   M2t   = (u16*)(ws + 0x2C10000);      // 512 KB [256 x 1024]

    hipMemsetAsync(ws, 0, 0x9000, stream);     // dv + de only

    prep_h<<<dim3(16, 128), 256, 0, stream>>>(H, Hb, Ht, dv, de);
    prep_x<<<dim3(4, 128), 256, 0, stream>>>(X, dv, Xst);

    // GEMM1: Maccp[z][f][e] = partial sum over k-slab z; M=256, N=1024,
    // K=8192, split-K=8, non-atomic partial stores. grid (16,4,8)=512 blocks.
    gemm_bt<0><<<dim3(16, 4, 8), 256, 0, stream>>>(
        Xst, Ht, 8192, 8192, 1024, Maccp, 1024, F_DIM * N_EDGES,
        nullptr, nullptr);

    // fold W at E-side: M2t[j][e] = W (sum_p Maccp / de) -> bf16 [256 x 1024]
    gemm_we<<<dim3(16, 4), 256, 0, stream>>>(W, Maccp, de, M2t);

    // GEMM2: out[n][j] = rsqrt(dv[n]) * sum_e Hb[n][e]*M2t[j][e] + b[j]
    gemm_bt<1><<<dim3(4, 128, 1), 256, 0, stream>>>(
        Hb, M2t, 1024, 1024, 1024, out, 256, 0, dv, b);
}

// Round 9
// 152.169 us; speedup vs baseline: 1.0424x; 1.0424x over previous
//
#include <hip/hip_runtime.h>
#include <hip/hip_bf16.h>
#include <stdint.h>

typedef __attribute__((ext_vector_type(8))) short bf16x8;
typedef __attribute__((ext_vector_type(4))) float f32x4;
typedef __attribute__((ext_vector_type(4))) unsigned int u32x4;
typedef __attribute__((ext_vector_type(2))) unsigned int u32x2;
typedef unsigned short u16;
typedef unsigned int u32;

#define N_NODES 8192
#define N_EDGES 1024
#define F_DIM   256

__device__ __forceinline__ u16 f2bf(float f) {
    union { float f; u32 u; } v; v.f = f;
    u32 u = v.u;
    u = (u + 0x7FFFu + ((u >> 16) & 1u)) >> 16;   // round-nearest-even
    return (u16)u;
}

// async 16B global -> LDS (direct-to-shared DMA; m97 ladder step).
// LDS dest semantics: wave-uniform base + lane*16 (no padding possible).
__device__ __forceinline__ void async16(const u16* g, u16* l) {
    __builtin_amdgcn_global_load_lds(
        (const __attribute__((address_space(1))) u32*)(const void*)g,
        (__attribute__((address_space(3))) u32*)(void*)l, 16, 0, 0);
}

// ---------------------------------------------------------------------------
// prep_h — R1/R6/R7 verbatim.
// One pass over H [8192 x 1024] fp32:
//   - Hb [8192 x 1024] bf16 (row-major, A-operand of GEMM2)
//   - Ht [1024 x 8192] bf16 (transposed via LDS, Bt-operand of GEMM1)
//   - dv[8192] row sums, de[1024] col sums (exact: sums of 0/1)
// ---------------------------------------------------------------------------
__global__ void prep_h(const float* __restrict__ H, u16* __restrict__ Hb,
                       u16* __restrict__ Ht, float* __restrict__ dv,
                       float* __restrict__ de) {
    __shared__ u16 tT[64 * 66];
    __shared__ float dv_s[64];
    __shared__ float de_s[64];
    const int tid = threadIdx.x;
    if (tid < 64) { dv_s[tid] = 0.f; de_s[tid] = 0.f; }
    __syncthreads();
    const int r0 = blockIdx.y * 64;
    const int c0 = blockIdx.x * 64;
    const int lr = tid >> 4;
    const int lc = (tid & 15) * 4;
    float cs0 = 0.f, cs1 = 0.f, cs2 = 0.f, cs3 = 0.f;
#pragma unroll
    for (int i = 0; i < 4; i++) {
        const int row = r0 + lr + i * 16;
        f32x4 v = *(const f32x4*)(&H[(size_t)row * N_EDGES + c0 + lc]);
        atomicAdd(&dv_s[lr + i * 16], v[0] + v[1] + v[2] + v[3]);
        cs0 += v[0]; cs1 += v[1]; cs2 += v[2]; cs3 += v[3];
        const u16 b0 = f2bf(v[0]), b1 = f2bf(v[1]), b2 = f2bf(v[2]), b3 = f2bf(v[3]);
        u32x2 pk; pk[0] = (u32)b0 | ((u32)b1 << 16); pk[1] = (u32)b2 | ((u32)b3 << 16);
        *(u32x2*)(&Hb[(size_t)row * N_EDGES + c0 + lc]) = pk;
        tT[(lc + 0) * 66 + lr + i * 16] = b0;
        tT[(lc + 1) * 66 + lr + i * 16] = b1;
        tT[(lc + 2) * 66 + lr + i * 16] = b2;
        tT[(lc + 3) * 66 + lr + i * 16] = b3;
    }
    atomicAdd(&de_s[lc + 0], cs0);
    atomicAdd(&de_s[lc + 1], cs1);
    atomicAdd(&de_s[lc + 2], cs2);
    atomicAdd(&de_s[lc + 3], cs3);
    __syncthreads();
    if (tid < 64) {
        atomicAdd(&dv[r0 + tid], dv_s[tid]);
        atomicAdd(&de[c0 + tid], de_s[tid]);
    }
#pragma unroll
    for (int i = 0; i < 4; i++) {
        const int er = lr + i * 16;
        const u16 b0 = tT[er * 66 + lc + 0];
        const u16 b1 = tT[er * 66 + lc + 1];
        const u16 b2 = tT[er * 66 + lc + 2];
        const u16 b3 = tT[er * 66 + lc + 3];
        u32x2 pk; pk[0] = (u32)b0 | ((u32)b1 << 16); pk[1] = (u32)b2 | ((u32)b3 << 16);
        *(u32x2*)(&Ht[(size_t)(c0 + er) * N_NODES + r0 + lc]) = pk;
    }
}

// ---------------------------------------------------------------------------
// prep_x — verbatim. Xst[f][n] = bf16(X[n][f]*rsqrt(dv[n])) [256 x 8192]
// ---------------------------------------------------------------------------
__global__ void prep_x(const float* __restrict__ X, const float* __restrict__ dv,
                       u16* __restrict__ Xst) {
    __shared__ u16 tT[64 * 66];
    const int tid = threadIdx.x;
    const int r0 = blockIdx.y * 64;
    const int c0 = blockIdx.x * 64;
    const int lr = tid >> 4;
    const int lc = (tid & 15) * 4;
#pragma unroll
    for (int i = 0; i < 4; i++) {
        const int row = r0 + lr + i * 16;
        const float s = rsqrtf(dv[row]);
        f32x4 v = *(const f32x4*)(&X[(size_t)row * F_DIM + c0 + lc]);
        tT[(lc + 0) * 66 + lr + i * 16] = f2bf(v[0] * s);
        tT[(lc + 1) * 66 + lr + i * 16] = f2bf(v[1] * s);
        tT[(lc + 2) * 66 + lr + i * 16] = f2bf(v[2] * s);
        tT[(lc + 3) * 66 + lr + i * 16] = f2bf(v[3] * s);
    }
    __syncthreads();
#pragma unroll
    for (int i = 0; i < 4; i++) {
        const int er = lr + i * 16;
        const u16 b0 = tT[er * 66 + lc + 0];
        const u16 b1 = tT[er * 66 + lc + 1];
        const u16 b2 = tT[er * 66 + lc + 2];
        const u16 b3 = tT[er * 66 + lc + 3];
        u32x2 pk; pk[0] = (u32)b0 | ((u32)b1 << 16); pk[1] = (u32)b2 | ((u32)b3 << 16);
        *(u32x2*)(&Xst[(size_t)(c0 + er) * N_NODES + r0 + lc]) = pk;
    }
}

// ---------------------------------------------------------------------------
// gemm_bt — R7 verbatim (measured best: 153.4 µs build).
// 64x64 tile, 256 thr, BK=64, global_load_lds width-16 staging, unpadded LDS.
// EPI 0: atomicAdd fp32 (split-K accumulate, GEMM1) — R8 proved atomics beat
//        partial stores here (L2-resident 1 MB region vs +15 MB round-trip).
// EPI 1: fp32 out = v*rsqrt(rowScale[row]) + bias[col]  (GEMM2 final)
// ---------------------------------------------------------------------------
template <int EPI>
__global__ void gemm_bt(const u16* __restrict__ A, const u16* __restrict__ Bt,
                        int lda, int ldb, int kSplit,
                        float* __restrict__ outF, int ldc,
                        const float* __restrict__ rowScale,
                        const float* __restrict__ bias) {
    __shared__ __align__(16) u16 As[64 * 64];
    __shared__ __align__(16) u16 Bs[64 * 64];
    const int tid = threadIdx.x;
    const int lane = tid & 63;
    const int wave = tid >> 6;          // 0..3
    const int wm = wave >> 1, wn = wave & 1;
    const int row16 = lane & 15;
    const int quad = lane >> 4;

    const int row0 = blockIdx.y * 64;
    const int col0 = blockIdx.x * 64;
    const int k0 = blockIdx.z * kSplit;
    const int k1 = k0 + kSplit;

    const int srow = lane >> 3;         // 0..7
    const int scol = (lane & 7) * 8;    // u16 units

    const u16* gA0 = A + (size_t)(row0 + wave * 16 + srow) * lda + scol;
    const u16* gB0 = Bt + (size_t)(col0 + wave * 16 + srow) * ldb + scol;
    const size_t rstep8A = (size_t)8 * lda;
    const size_t rstep8B = (size_t)8 * ldb;
    u16* lA0 = &As[(wave * 16) * 64];
    u16* lB0 = &Bs[(wave * 16) * 64];

    f32x4 acc[2][2] = {};

    for (int k = k0; k < k1; k += 64) {
        async16(gA0 + k, lA0);
        async16(gA0 + k + rstep8A, lA0 + 8 * 64);
        async16(gB0 + k, lB0);
        async16(gB0 + k + rstep8B, lB0 + 8 * 64);
        __syncthreads();
#pragma unroll
        for (int ks = 0; ks < 2; ks++) {
            bf16x8 af[2], bfr[2];
#pragma unroll
            for (int t = 0; t < 2; t++) {
                af[t]  = *(const bf16x8*)(&As[(wm * 32 + t * 16 + row16) * 64 + ks * 32 + quad * 8]);
                bfr[t] = *(const bf16x8*)(&Bs[(wn * 32 + t * 16 + row16) * 64 + ks * 32 + quad * 8]);
            }
#pragma unroll
            for (int tm = 0; tm < 2; tm++)
#pragma unroll
                for (int tn = 0; tn < 2; tn++)
                    acc[tm][tn] = __builtin_amdgcn_mfma_f32_16x16x32_bf16(
                        af[tm], bfr[tn], acc[tm][tn], 0, 0, 0);
        }
        __syncthreads();
    }

#pragma unroll
    for (int tm = 0; tm < 2; tm++) {
#pragma unroll
        for (int tn = 0; tn < 2; tn++) {
            const int col = col0 + wn * 32 + tn * 16 + row16;
#pragma unroll
            for (int r = 0; r < 4; r++) {
                const int row = row0 + wm * 32 + tm * 16 + quad * 4 + r;
                float v = acc[tm][tn][r];
                if (EPI == 0) {
                    atomicAdd(&outF[(size_t)row * ldc + col], v);
                } else {
                    outF[(size_t)row * ldc + col] =
                        v * rsqrtf(rowScale[row]) + bias[col];
                }
            }
        }
    }
}

// ---------------------------------------------------------------------------
// gemm_we — R7 verbatim. M2t[j][e] = sum_f W[j][f] * Macc[f][e] / de[e] (bf16)
// ---------------------------------------------------------------------------
__global__ void gemm_we(const float* __restrict__ W, const float* __restrict__ Macc,
                        const float* __restrict__ de, u16* __restrict__ M2t) {
    __shared__ u16 As[64 * 72];
    __shared__ u16 Bs[64 * 72];
    const int tid = threadIdx.x;
    const int lane = tid & 63;
    const int wave = tid >> 6;
    const int wm = wave >> 1, wn = wave & 1;
    const int row16 = lane & 15;
    const int quad = lane >> 4;

    const int j0 = blockIdx.y * 64;
    const int e0 = blockIdx.x * 64;

    const int sr = tid >> 2;
    const int fb = (tid & 3) * 16;
    const int lr = tid >> 4;
    const int lc = (tid & 15) * 4;

    f32x4 de4 = *(const f32x4*)(&de[e0 + lc]);
    f32x4 dei = {1.f / de4[0], 1.f / de4[1], 1.f / de4[2], 1.f / de4[3]};

    f32x4 acc[2][2] = {};

    for (int k = 0; k < 256; k += 64) {
#pragma unroll
        for (int s = 0; s < 4; s++) {
            f32x4 w = *(const f32x4*)(&W[(size_t)(j0 + sr) * 256 + k + fb + s * 4]);
            u32x2 pk;
            pk[0] = (u32)f2bf(w[0]) | ((u32)f2bf(w[1]) << 16);
            pk[1] = (u32)f2bf(w[2]) | ((u32)f2bf(w[3]) << 16);
            *(u32x2*)(&As[sr * 72 + fb + s * 4]) = pk;
        }
#pragma unroll
        for (int i = 0; i < 4; i++) {
            const int f = k + lr + i * 16;
            f32x4 m = *(const f32x4*)(&Macc[(size_t)f * N_EDGES + e0 + lc]);
            Bs[(lc + 0) * 72 + lr + i * 16] = f2bf(m[0] * dei[0]);
            Bs[(lc + 1) * 72 + lr + i * 16] = f2bf(m[1] * dei[1]);
            Bs[(lc + 2) * 72 + lr + i * 16] = f2bf(m[2] * dei[2]);
            Bs[(lc + 3) * 72 + lr + i * 16] = f2bf(m[3] * dei[3]);
        }
        __syncthreads();
#pragma unroll
        for (int ks = 0; ks < 2; ks++) {
            bf16x8 af[2], bfr[2];
#pragma unroll
            for (int i = 0; i < 2; i++)
                af[i] = *(const bf16x8*)(&As[(wm * 32 + i * 16 + row16) * 72 + ks * 32 + quad * 8]);
#pragma unroll
            for (int j = 0; j < 2; j++)
                bfr[j] = *(const bf16x8*)(&Bs[(wn * 32 + j * 16 + row16) * 72 + ks * 32 + quad * 8]);
#pragma unroll
            for (int i = 0; i < 2; i++)
#pragma unroll
                for (int j = 0; j < 2; j++)
                    acc[i][j] = __builtin_amdgcn_mfma_f32_16x16x32_bf16(
                        af[i], bfr[j], acc[i][j], 0, 0, 0);
        }
        __syncthreads();
    }

#pragma unroll
    for (int i = 0; i < 2; i++) {
#pragma unroll
        for (int j = 0; j < 2; j++) {
            const int col = e0 + wn * 32 + j * 16 + row16;
#pragma unroll
            for (int r = 0; r < 4; r++) {
                const int row = j0 + wm * 32 + i * 16 + quad * 4 + r;
                M2t[(size_t)row * N_EDGES + col] = f2bf(acc[i][j][r]);
            }
        }
    }
}

// ---------------------------------------------------------------------------
extern "C" void kernel_launch(void* const* d_in, const int* in_sizes, int n_in,
                              void* d_out, int out_size, void* d_ws, size_t ws_size,
                              hipStream_t stream) {
    (void)in_sizes; (void)n_in; (void)out_size; (void)ws_size;
    const float* X = (const float*)d_in[0];   // [8192 x 256]
    const float* H = (const float*)d_in[1];   // [8192 x 1024]
    const float* W = (const float*)d_in[2];   // [256 x 256]
    const float* b = (const float*)d_in[3];   // [256]
    float* out = (float*)d_out;               // [8192 x 256] fp32

    char* ws = (char*)d_ws;                    // R7 layout
    float* Macc = (float*)(ws);                // 1 MB   [256 x 1024] fp32
    float* dv   = (float*)(ws + 0x100000);     // 32 KB
    float* de   = (float*)(ws + 0x108000);     // 4 KB
    u16*   Hb   = (u16*)(ws + 0x110000);       // 16 MB  [8192 x 1024]
    u16*   Ht   = (u16*)(ws + 0x1110000);      // 16 MB  [1024 x 8192]
    u16*   Xst  = (u16*)(ws + 0x2110000);      // 4 MB   [256 x 8192]
    u16*   M2t  = (u16*)(ws + 0x2510000);      // 512 KB [256 x 1024]

    hipMemsetAsync(ws, 0, 0x109000, stream);   // Macc + dv + de

    prep_h<<<dim3(16, 128), 256, 0, stream>>>(H, Hb, Ht, dv, de);
    prep_x<<<dim3(4, 128), 256, 0, stream>>>(X, dv, Xst);

    // GEMM1: Macc[f][e] += Xst * Ht^T; M=256, N=1024, K=8192, split-K=8.
    gemm_bt<0><<<dim3(16, 4, 8), 256, 0, stream>>>(
        Xst, Ht, 8192, 8192, 1024, Macc, 1024, nullptr, nullptr);

    // fold W at E-side: M2t[j][e] = W (Macc/de) -> bf16 [256 x 1024]
    gemm_we<<<dim3(16, 4), 256, 0, stream>>>(W, Macc, de, M2t);

    // GEMM2: out[n][j] = rsqrt(dv[n]) * sum_e Hb[n][e]*M2t[j][e] + b[j]
    gemm_bt<1><<<dim3(4, 128, 1), 256, 0, stream>>>(
        Hb, M2t, 1024, 1024, 1024, out, 256, dv, b);
}